// Round 7
// baseline (580.956 us; speedup 1.0000x reference)
//
#include <hip/hip_runtime.h>
#include <hip/hip_bf16.h>
#include <math.h>

using short8 = __attribute__((ext_vector_type(8))) short;
using f32x4  = __attribute__((ext_vector_type(4))) float;

__device__ __forceinline__ unsigned short f2bf(float x) {
    return __builtin_bit_cast(unsigned short, __float2bfloat16(x));
}
__device__ __forceinline__ float bf2f(unsigned short u) {
    unsigned int x = ((unsigned int)u) << 16;
    return __builtin_bit_cast(float, x);
}

#define MFMA16(A,B,C) __builtin_amdgcn_mfma_f32_16x16x32_bf16((A),(B),(C),0,0,0)

// ---------------- helpers ----------------
__device__ __forceinline__ void ld16(const float* __restrict__ p, float* a) {
    const float4* q = (const float4*)p;
    float4 v0 = q[0], v1 = q[1], v2 = q[2], v3 = q[3];
    a[0]=v0.x; a[1]=v0.y; a[2]=v0.z; a[3]=v0.w;
    a[4]=v1.x; a[5]=v1.y; a[6]=v1.z; a[7]=v1.w;
    a[8]=v2.x; a[9]=v2.y; a[10]=v2.z; a[11]=v2.w;
    a[12]=v3.x; a[13]=v3.y; a[14]=v3.z; a[15]=v3.w;
}

// ---------------- CSR build ----------------
__global__ __launch_bounds__(256) void k_count(const int* __restrict__ ei, int* __restrict__ cnt, int E) {
    int e = blockIdx.x * blockDim.x + threadIdx.x;
    if (e < E) atomicAdd(&cnt[ei[E + e]], 1);
}

__global__ __launch_bounds__(256) void k_scanA(const int* __restrict__ cnt, int* __restrict__ offs,
                                               int* __restrict__ bsum, int N) {
    __shared__ int s[256];
    int i = blockIdx.x * 256 + threadIdx.x;
    int v = (i < N) ? cnt[i] : 0;
    s[threadIdx.x] = v;
    __syncthreads();
    #pragma unroll
    for (int d = 1; d < 256; d <<= 1) {
        int t = (threadIdx.x >= d) ? s[threadIdx.x - d] : 0;
        __syncthreads();
        s[threadIdx.x] += t;
        __syncthreads();
    }
    if (i < N) offs[i] = s[threadIdx.x] - v;
    if (threadIdx.x == 255) bsum[blockIdx.x] = s[255];
}

__global__ __launch_bounds__(256) void k_scanB(int* __restrict__ bsum, int nb) {
    __shared__ int s[256];
    int v = (threadIdx.x < nb) ? bsum[threadIdx.x] : 0;
    s[threadIdx.x] = v;
    __syncthreads();
    #pragma unroll
    for (int d = 1; d < 256; d <<= 1) {
        int t = (threadIdx.x >= d) ? s[threadIdx.x - d] : 0;
        __syncthreads();
        s[threadIdx.x] += t;
        __syncthreads();
    }
    if (threadIdx.x < nb) bsum[threadIdx.x] = s[threadIdx.x] - v;
}

__global__ __launch_bounds__(256) void k_scanC(int* __restrict__ offs, const int* __restrict__ bsum, int N) {
    int i = blockIdx.x * 256 + threadIdx.x;
    if (i < N) offs[i] += bsum[blockIdx.x];
}

__global__ __launch_bounds__(256) void k_fillD(const int* __restrict__ ei, const int* __restrict__ offs,
                                               int* __restrict__ cursor, int* __restrict__ slotOf,
                                               int* __restrict__ srcSl, int E) {
    int e = blockIdx.x * blockDim.x + threadIdx.x;
    if (e < E) {
        int d = ei[E + e];
        int slot = offs[d] + atomicAdd(&cursor[d], 1);
        slotOf[e] = slot;
        srcSl[slot] = ei[e];
    }
}

// ---------------- edge MLP a = relu(ea@w1+b1), stored in slot order (once) ----------------
__global__ __launch_bounds__(256) void k_a(
    const float* __restrict__ ea, const float* __restrict__ w1,
    const float* __restrict__ b1, const int* __restrict__ slotOf,
    float* __restrict__ aSl, int E)
{
    int e = blockIdx.x * 256 + threadIdx.x;
    if (e >= E) return;
    const float4* p = (const float4*)(ea + (size_t)e * 8);
    float4 v0 = p[0], v1 = p[1];
    float eav[8] = {v0.x, v0.y, v0.z, v0.w, v1.x, v1.y, v1.z, v1.w};
    float a[16];
    #pragma unroll
    for (int k = 0; k < 16; k++) a[k] = b1[k];
    #pragma unroll
    for (int q = 0; q < 8; q++) {
        float ev = eav[q];
        #pragma unroll
        for (int k = 0; k < 16; k++) a[k] += ev * w1[q * 16 + k];
    }
    int slot = slotOf[e];
    float4* o = (float4*)(aSl + (size_t)slot * 16);
    o[0] = make_float4(fmaxf(a[0],0.f), fmaxf(a[1],0.f), fmaxf(a[2],0.f), fmaxf(a[3],0.f));
    o[1] = make_float4(fmaxf(a[4],0.f), fmaxf(a[5],0.f), fmaxf(a[6],0.f), fmaxf(a[7],0.f));
    o[2] = make_float4(fmaxf(a[8],0.f), fmaxf(a[9],0.f), fmaxf(a[10],0.f), fmaxf(a[11],0.f));
    o[3] = make_float4(fmaxf(a[12],0.f), fmaxf(a[13],0.f), fmaxf(a[14],0.f), fmaxf(a[15],0.f));
}

// ---------------- per-layer gather: hSl[slot][c] = BN(h[srcSl[slot]][c]) ----------------
// massively parallel -> random-gather latency hidden by TLP; k_fuse2 then streams.
template<int BNPREV>
__global__ __launch_bounds__(256) void k_gather(
    const float* __restrict__ hraw, const int* __restrict__ srcSl,
    const float* __restrict__ statsPrev, const float* __restrict__ gPrev,
    const float* __restrict__ bePrev, float* __restrict__ hSl,
    int E16, float invN)
{
    __shared__ float scsh[32];
    if (BNPREV) {
        if (threadIdx.x < 16) {
            int o = threadIdx.x;
            float m = statsPrev[o] * invN;
            float var = statsPrev[16 + o] * invN - m * m;
            float sc = gPrev[o] * rsqrtf(var + 1e-5f);
            scsh[o] = sc;
            scsh[16 + o] = bePrev[o] - m * sc;
        }
        __syncthreads();
    }
    int t = blockIdx.x * 256 + threadIdx.x;
    if (t >= E16) return;
    int slot = t >> 4, c = t & 15;
    int src = srcSl[slot];
    float v = hraw[(size_t)src * 16 + c];
    if (BNPREV) v = v * scsh[c] + scsh[16 + c];
    hSl[t] = v;
}

// ---------------- W2cat fragment prep (once): logical K = i*18+k, K=288 = 9 tiles ----------
//   k<16 -> w2[k][i][o] ; k==16 -> b2[i][o] (B-val = sum h) ; k==17 -> root_l[i][o] (B-val = hBN)
// sigma(g,t,j) = 32t+8g+j, same mapping used for the A-side LDS read in k_fuse2.
// hi/lo bf16 split for ~fp32 accuracy.
__global__ void k_w2prep(const float* __restrict__ w2, const float* __restrict__ b2,
                         const float* __restrict__ r0, const float* __restrict__ r1,
                         const float* __restrict__ r2, const float* __restrict__ r3,
                         unsigned short* __restrict__ wf2)
{
    int tid = blockIdx.x * 256 + threadIdx.x;
    if (tid >= 2304) return;                      // 4 layers * 9 tiles * 64 lanes
    int l = tid / 576, rem = tid % 576;
    int t = rem / 64, lane = rem % 64;
    int g = lane >> 4, o = lane & 15;
    const float* roots[4] = {r0, r1, r2, r3};
    unsigned short hi8[8], lo8[8];
    #pragma unroll
    for (int j = 0; j < 8; j++) {
        int kp = 32 * t + 8 * g + j;
        int i = kp / 18, k = kp % 18;
        float v;
        if (k < 16)      v = w2[k * 256 + i * 16 + o];
        else if (k == 16) v = b2[i * 16 + o];
        else              v = roots[l][i * 16 + o];
        unsigned short h = f2bf(v);
        hi8[j] = h;
        lo8[j] = f2bf(v - bf2f(h));
    }
    unsigned short* oh = wf2 + (size_t)l * 9216 + (t * 2 + 0) * 512 + lane * 8;
    unsigned short* ol = wf2 + (size_t)l * 9216 + (t * 2 + 1) * 512 + lane * 8;
    #pragma unroll
    for (int j = 0; j < 8; j++) { oh[j] = hi8[j]; ol[j] = lo8[j]; }
}

// ---------------- fused conv layer v2: streamed edge phase + MFMA contraction ------------
// 128 threads = 2 waves; wave owns 16 nodes. Edge phase: 4 rounds of 4 nodes x 16 lanes,
// B[n][k][i] accumulated fp32 in regs from sequential hSl/aSl streams, written to LDS as
// bf16 hi+lo. Contraction: 9 K-tiles x 3 MFMAs (hi*hi + hi*lo + lo*hi) vs prepped W2cat
// fragments; b2/root/cb folded into the GEMM. Output relu + BN-stats via shuffle+atomics.
template<int BNPREV>
__global__ __launch_bounds__(128) void k_fuse2(
    const float* __restrict__ hraw, const float* __restrict__ statsPrev,
    const float* __restrict__ gPrev, const float* __restrict__ bePrev,
    const int* __restrict__ offs, const int* __restrict__ cnt,
    const float* __restrict__ hSl, const float* __restrict__ aSl,
    const unsigned short* __restrict__ wfragL, const float* __restrict__ cb,
    float* __restrict__ hout, float* __restrict__ statsCur,
    int N, float invN)
{
    __shared__ unsigned short Bl[2][2][16][296];   // [wave][hi/lo][n_local][k'] (stride 296: bank-clean)
    __shared__ float scsh[32];
    int tid = threadIdx.x;
    int w = tid >> 6, lane = tid & 63;
    int g = lane >> 4, c = lane & 15;
    if (BNPREV) {
        if (tid < 16) {
            float m = statsPrev[tid] * invN;
            float var = statsPrev[16 + tid] * invN - m * m;
            float sc = gPrev[tid] * rsqrtf(var + 1e-5f);
            scsh[tid] = sc;
            scsh[16 + tid] = bePrev[tid] - m * sc;
        }
        __syncthreads();
    }
    float scC = BNPREV ? scsh[c] : 1.f;
    float shC = BNPREV ? scsh[16 + c] : 0.f;
    int base = blockIdx.x * 32 + w * 16;

    const f32x4* aSl4 = (const f32x4*)aSl;

    // ---- edge phase: 4 rounds x (4 nodes x 16 c-lanes) ----
    for (int r = 0; r < 4; r++) {
        int nl = r * 4 + g;
        int node = base + nl;
        float B[18];
        #pragma unroll
        for (int k = 0; k < 18; k++) B[k] = 0.f;
        if (node < N) {
            B[17] = hraw[(size_t)node * 16 + c] * scC + shC;   // hBN -> root row
            int start = offs[node], deg = cnt[node];
            int j = 0;
            for (; j + 2 <= deg; j += 2) {                     // 2-edge unroll for MLP
                size_t s0 = (size_t)(start + j), s1 = s0 + 1;
                float hs0 = hSl[s0 * 16 + c];
                float hs1 = hSl[s1 * 16 + c];
                f32x4 a00 = aSl4[s0*4+0], a01 = aSl4[s0*4+1], a02 = aSl4[s0*4+2], a03 = aSl4[s0*4+3];
                f32x4 a10 = aSl4[s1*4+0], a11 = aSl4[s1*4+1], a12 = aSl4[s1*4+2], a13 = aSl4[s1*4+3];
                #pragma unroll
                for (int q = 0; q < 4; q++) {
                    B[q]      += a00[q]*hs0; B[4+q]  += a01[q]*hs0;
                    B[8+q]    += a02[q]*hs0; B[12+q] += a03[q]*hs0;
                    B[q]      += a10[q]*hs1; B[4+q]  += a11[q]*hs1;
                    B[8+q]    += a12[q]*hs1; B[12+q] += a13[q]*hs1;
                }
                B[16] += hs0 + hs1;
            }
            if (j < deg) {
                size_t s0 = (size_t)(start + j);
                float hs0 = hSl[s0 * 16 + c];
                f32x4 a00 = aSl4[s0*4+0], a01 = aSl4[s0*4+1], a02 = aSl4[s0*4+2], a03 = aSl4[s0*4+3];
                #pragma unroll
                for (int q = 0; q < 4; q++) {
                    B[q]      += a00[q]*hs0; B[4+q]  += a01[q]*hs0;
                    B[8+q]    += a02[q]*hs0; B[12+q] += a03[q]*hs0;
                }
                B[16] += hs0;
            }
        }
        // write hi/lo planes: thread's 18 values are contiguous k' = c*18 + (0..17)
        #pragma unroll
        for (int p = 0; p < 9; p++) {
            float v0 = B[2*p], v1 = B[2*p+1];
            unsigned short h0 = f2bf(v0), h1 = f2bf(v1);
            unsigned short e0 = f2bf(v0 - bf2f(h0)), e1 = f2bf(v1 - bf2f(h1));
            *(unsigned int*)&Bl[w][0][nl][c*18 + 2*p] = (unsigned int)h0 | ((unsigned int)h1 << 16);
            *(unsigned int*)&Bl[w][1][nl][c*18 + 2*p] = (unsigned int)e0 | ((unsigned int)e1 << 16);
        }
    }

    // ---- contraction: A rows = n_local (lane&15), slot-group g; W frags prepped with same sigma
    float cbv = cb[c];
    f32x4 acc0 = {cbv, cbv, cbv, cbv};
    f32x4 acc1 = {0.f, 0.f, 0.f, 0.f};
    f32x4 acc2 = {0.f, 0.f, 0.f, 0.f};
    const short8* wf = (const short8*)wfragL;
    #pragma unroll
    for (int t = 0; t < 9; t++) {
        short8 whi = wf[(t*2+0)*64 + lane];
        short8 wlo = wf[(t*2+1)*64 + lane];
        short8 ahi = *(const short8*)&Bl[w][0][c][32*t + 8*g];
        short8 alo = *(const short8*)&Bl[w][1][c][32*t + 8*g];
        acc0 = MFMA16(ahi, whi, acc0);
        acc1 = MFMA16(ahi, wlo, acc1);
        acc2 = MFMA16(alo, whi, acc2);
    }

    float s1 = 0.f, s2 = 0.f;
    #pragma unroll
    for (int rr = 0; rr < 4; rr++) {
        int node = base + 4*g + rr;
        float v = fmaxf(acc0[rr] + acc1[rr] + acc2[rr], 0.f);
        if (node < N) {
            hout[(size_t)node * 16 + c] = v;
            s1 += v; s2 += v * v;
        }
    }
    s1 += __shfl_xor(s1, 16); s1 += __shfl_xor(s1, 32);
    s2 += __shfl_xor(s2, 16); s2 += __shfl_xor(s2, 32);
    if (lane < 16) {
        atomicAdd(&statsCur[c], s1);
        atomicAdd(&statsCur[16 + c], s2);
    }
}

// ---------------- mu / logvar / reparameterize (BN of layer 4 inlined) ----------------
__global__ __launch_bounds__(256) void k_z(
    const float* __restrict__ hraw, const float* __restrict__ stats4,
    const float* __restrict__ g4, const float* __restrict__ be4,
    const float* __restrict__ mu_w, const float* __restrict__ mu_b,
    const float* __restrict__ lv_w, const float* __restrict__ lv_b,
    const float* __restrict__ eps, float* __restrict__ z, int N, float invN)
{
    __shared__ float scsh[32];
    int tid = threadIdx.x;
    if (tid < 16) {
        float m = stats4[tid] * invN;
        float var = stats4[16 + tid] * invN - m * m;
        float sc = g4[tid] * rsqrtf(var + 1e-5f);
        scsh[tid] = sc;
        scsh[16 + tid] = be4[tid] - m * sc;
    }
    __syncthreads();
    int t = blockIdx.x * 256 + tid;
    if (t >= N * 16) return;
    int n = t >> 4, o = t & 15;
    float hr[16];
    ld16(hraw + (size_t)n * 16, hr);
    float mu = mu_b[o], lv = lv_b[o];
    #pragma unroll
    for (int j = 0; j < 16; j++) {
        float hv = hr[j] * scsh[j] + scsh[16 + j];
        mu += hv * mu_w[j * 16 + o];
        lv += hv * lv_w[j * 16 + o];
    }
    lv = fminf(lv, 10.f);
    z[t] = mu + eps[t] * expf(0.5f * lv);
}

// ---------------- decoder weight pre-swizzle to MFMA fragment order (bf16) ----------------
__global__ void k_wprep(const float* __restrict__ dw0, const float* __restrict__ dw1,
                        const float* __restrict__ dw2, const float* __restrict__ dw3,
                        const float* __restrict__ dw4, unsigned short* __restrict__ wfrag)
{
    int tid = blockIdx.x * 256 + threadIdx.x;
    if (tid >= 1920) return;
    int f = tid >> 6, lane = tid & 63, g = lane >> 4, c = lane & 15;
    float v[8];
    if (f < 4) {
        int mt = f;
        #pragma unroll
        for (int j = 0; j < 8; j++) v[j] = dw0[(8*g + j) * 64 + 16*mt + c];
    } else if (f < 28) {
        int fl = f - 4;
        const float* W = (fl >> 3) == 0 ? dw1 : ((fl >> 3) == 1 ? dw2 : dw3);
        int mt = (fl & 7) >> 1, kt = fl & 1;
        #pragma unroll
        for (int j = 0; j < 8; j++) {
            int in = 16*(2*kt + (j>>2)) + 4*g + (j&3);
            v[j] = W[in * 64 + 16*mt + c];
        }
    } else {
        int kt = f - 28;
        #pragma unroll
        for (int j = 0; j < 8; j++) {
            int in = 16*(2*kt + (j>>2)) + 4*g + (j&3);
            v[j] = (c < 8) ? dw4[in * 8 + c] : 0.f;
        }
    }
    unsigned short* o = wfrag + (size_t)tid * 8;
    #pragma unroll
    for (int j = 0; j < 8; j++) o[j] = f2bf(v[j]);
}

// ---------------- MFMA decoder ----------------
#define REPACK() do { \
    float av[16]; \
    _Pragma("unroll") for (int mt = 0; mt < 4; mt++) { \
        _Pragma("unroll") for (int r = 0; r < 4; r++) av[mt*4 + r] = acc[mt][r]; } \
    _Pragma("unroll") for (int kt = 0; kt < 2; kt++) { \
        _Pragma("unroll") for (int j = 0; j < 8; j++) \
            a2[kt][j] = (short)f2bf(fmaxf(av[(2*kt + (j>>2))*4 + (j&3)], 0.f)); } \
} while (0)

#define DENSE(WF, DB) do { \
    _Pragma("unroll") for (int mt = 0; mt < 4; mt++) acc[mt] = *(const f32x4*)((DB) + 16*mt + 4*g); \
    _Pragma("unroll") for (int mt = 0; mt < 4; mt++) acc[mt] = MFMA16(WF[mt][0], a2[0], acc[mt]); \
    _Pragma("unroll") for (int mt = 0; mt < 4; mt++) acc[mt] = MFMA16(WF[mt][1], a2[1], acc[mt]); \
    REPACK(); \
} while (0)

__global__ __launch_bounds__(256) void k_dec(
    const float* __restrict__ z, const int* __restrict__ ei,
    const unsigned short* __restrict__ wfrag,
    const float* __restrict__ db0, const float* __restrict__ db1,
    const float* __restrict__ db2, const float* __restrict__ db3,
    const float* __restrict__ db4,
    float* __restrict__ out, int E, int T, int totalTiles)
{
    int wid = blockIdx.x * 4 + (threadIdx.x >> 6);
    int lane = threadIdx.x & 63;
    int g = lane >> 4, c = lane & 15;
    int t0 = wid * T;
    if (t0 >= totalTiles) return;
    int t1 = min(t0 + T, totalTiles);

    const short8* wf = (const short8*)wfrag;
    short8 w0f[4], wfa[4][2], wfb[4][2], wfc[4][2], w4f[2];
    #pragma unroll
    for (int mt = 0; mt < 4; mt++) w0f[mt] = wf[mt * 64 + lane];
    #pragma unroll
    for (int mt = 0; mt < 4; mt++) {
        #pragma unroll
        for (int kt = 0; kt < 2; kt++) {
            wfa[mt][kt] = wf[(4  + mt*2 + kt) * 64 + lane];
            wfb[mt][kt] = wf[(12 + mt*2 + kt) * 64 + lane];
            wfc[mt][kt] = wf[(20 + mt*2 + kt) * 64 + lane];
        }
    }
    w4f[0] = wf[28 * 64 + lane];
    w4f[1] = wf[29 * 64 + lane];

    int eiOfs = (g < 2) ? 0 : E;
    int zofs = (g & 1) * 8;

    int node = ei[eiOfs + min(t0 * 16 + c, E - 1)];
    f32x4 zv0 = *(const f32x4*)(z + (size_t)node * 16 + zofs);
    f32x4 zv1 = *(const f32x4*)(z + (size_t)node * 16 + zofs + 4);
    int node_n = 0;
    if (t0 + 1 < t1) node_n = ei[eiOfs + min((t0 + 1) * 16 + c, E - 1)];

    for (int t = t0; t < t1; ++t) {
        f32x4 zn0 = {0.f,0.f,0.f,0.f}, zn1 = {0.f,0.f,0.f,0.f};
        if (t + 1 < t1) {
            zn0 = *(const f32x4*)(z + (size_t)node_n * 16 + zofs);
            zn1 = *(const f32x4*)(z + (size_t)node_n * 16 + zofs + 4);
        }
        int node_nn = 0;
        if (t + 2 < t1) node_nn = ei[eiOfs + min((t + 2) * 16 + c, E - 1)];

        short8 af0;
        #pragma unroll
        for (int j = 0; j < 4; j++) {
            af0[j]     = (short)f2bf(zv0[j]);
            af0[4 + j] = (short)f2bf(zv1[j]);
        }
        f32x4 acc[4];
        short8 a2[2];
        #pragma unroll
        for (int mt = 0; mt < 4; mt++) acc[mt] = *(const f32x4*)(db0 + 16*mt + 4*g);
        #pragma unroll
        for (int mt = 0; mt < 4; mt++) acc[mt] = MFMA16(w0f[mt], af0, acc[mt]);
        REPACK();

        DENSE(wfa, db1);
        DENSE(wfb, db2);
        DENSE(wfc, db3);

        f32x4 o4;
        if (g < 2) o4 = *(const f32x4*)(db4 + 4*g);
        else { o4[0]=0.f; o4[1]=0.f; o4[2]=0.f; o4[3]=0.f; }
        o4 = MFMA16(w4f[0], a2[0], o4);
        o4 = MFMA16(w4f[1], a2[1], o4);

        int e = t * 16 + c;
        if (g < 2 && e < E) *(f32x4*)(out + (size_t)e * 8 + 4*g) = o4;

        zv0 = zn0; zv1 = zn1; node_n = node_nn;
    }
}

// ---------------- launch ----------------
extern "C" void kernel_launch(void* const* d_in, const int* in_sizes, int n_in,
                              void* d_out, int out_size, void* d_ws, size_t ws_size,
                              hipStream_t stream)
{
    const float* x   = (const float*)d_in[0];
    const int*   ei  = (const int*)d_in[1];
    const float* ea  = (const float*)d_in[2];
    const float* eps = (const float*)d_in[3];
    const float* w1  = (const float*)d_in[4];
    const float* b1  = (const float*)d_in[5];
    const float* w2  = (const float*)d_in[6];
    const float* b2  = (const float*)d_in[7];
    const float* root[4]; const float* cb[4]; const float* g[4]; const float* be[4];
    for (int l = 0; l < 4; l++) {
        root[l] = (const float*)d_in[8 + 4*l];
        cb[l]   = (const float*)d_in[9 + 4*l];
        g[l]    = (const float*)d_in[10 + 4*l];
        be[l]   = (const float*)d_in[11 + 4*l];
    }
    const float* mu_w = (const float*)d_in[24];
    const float* mu_b = (const float*)d_in[25];
    const float* lv_w = (const float*)d_in[26];
    const float* lv_b = (const float*)d_in[27];
    const float* dw[5]; const float* db[5];
    for (int i = 0; i < 5; i++) {
        dw[i] = (const float*)d_in[28 + 2*i];
        db[i] = (const float*)d_in[29 + 2*i];
    }
    float* out = (float*)d_out;

    int N = in_sizes[0] / 16;
    int E = in_sizes[2] / 8;
    float invN = 1.0f / N;

    // ---- workspace layout ----
    int*   cnt      = (int*)d_ws;                 // N
    int*   cursor   = cnt + N;                    // N
    float* statsAll = (float*)(cursor + N);       // 128 (4 layers x 32)
    int*   offs     = (int*)(statsAll + 128);     // N
    int*   bsum     = offs + N;                   // 256
    int*   slotOf   = bsum + 256;                 // E
    int*   srcSl    = slotOf + E;                 // E
    float* aSl      = (float*)(srcSl + E);        // E*16
    float* hSl      = aSl + (size_t)E * 16;       // E*16
    float* hA       = hSl + (size_t)E * 16;       // N*16
    float* hB       = hA + (size_t)N * 16;        // N*16
    float* zbuf     = hB + (size_t)N * 16;        // N*16
    unsigned short* wfrag  = (unsigned short*)(zbuf + (size_t)N * 16); // 15360 (decoder)
    unsigned short* wfrag2 = wfrag + 15360;       // 36864 (conv W2cat hi/lo, 4 layers)

    int nbScan = (N + 255) / 256;

    hipMemsetAsync(cnt, 0, ((size_t)2 * N + 128) * sizeof(int), stream);

    // ---- weight preps (independent) ----
    k_wprep<<<8, 256, 0, stream>>>(dw[0], dw[1], dw[2], dw[3], dw[4], wfrag);
    k_w2prep<<<9, 256, 0, stream>>>(w2, b2, root[0], root[1], root[2], root[3], wfrag2);

    // ---- dst-CSR ----
    k_count<<<(E + 255) / 256, 256, 0, stream>>>(ei, cnt, E);
    k_scanA<<<nbScan, 256, 0, stream>>>(cnt, offs, bsum, N);
    k_scanB<<<1, 256, 0, stream>>>(bsum, nbScan);
    k_scanC<<<nbScan, 256, 0, stream>>>(offs, bsum, N);
    k_fillD<<<(E + 255) / 256, 256, 0, stream>>>(ei, offs, cursor, slotOf, srcSl, E);

    // ---- edge MLP once (layer-independent) ----
    k_a<<<(E + 255) / 256, 256, 0, stream>>>(ea, w1, b1, slotOf, aSl, E);

    int E16 = E * 16;
    int nbG = (E16 + 255) / 256;
    int nbF = (N + 31) / 32;

    // ---- 4 conv layers: gather(BN) -> fuse2 ----
    k_gather<0><<<nbG, 256, 0, stream>>>(x, srcSl, nullptr, nullptr, nullptr, hSl, E16, invN);
    k_fuse2<0><<<nbF, 128, 0, stream>>>(x, nullptr, nullptr, nullptr, offs, cnt, hSl, aSl,
                                        wfrag2 + 0 * 9216, cb[0], hA, statsAll + 0, N, invN);

    k_gather<1><<<nbG, 256, 0, stream>>>(hA, srcSl, statsAll + 0, g[0], be[0], hSl, E16, invN);
    k_fuse2<1><<<nbF, 128, 0, stream>>>(hA, statsAll + 0, g[0], be[0], offs, cnt, hSl, aSl,
                                        wfrag2 + 1 * 9216, cb[1], hB, statsAll + 32, N, invN);

    k_gather<1><<<nbG, 256, 0, stream>>>(hB, srcSl, statsAll + 32, g[1], be[1], hSl, E16, invN);
    k_fuse2<1><<<nbF, 128, 0, stream>>>(hB, statsAll + 32, g[1], be[1], offs, cnt, hSl, aSl,
                                        wfrag2 + 2 * 9216, cb[2], hA, statsAll + 64, N, invN);

    k_gather<1><<<nbG, 256, 0, stream>>>(hA, srcSl, statsAll + 64, g[2], be[2], hSl, E16, invN);
    k_fuse2<1><<<nbF, 128, 0, stream>>>(hA, statsAll + 64, g[2], be[2], offs, cnt, hSl, aSl,
                                        wfrag2 + 3 * 9216, cb[3], hB, statsAll + 96, N, invN);

    k_z<<<(N * 16 + 255) / 256, 256, 0, stream>>>(hB, statsAll + 96, g[3], be[3],
                                                  mu_w, mu_b, lv_w, lv_b, eps, zbuf, N, invN);

    int totalTiles = (E + 15) >> 4;
    int T = (totalTiles + 4095) / 4096;
    int wavesUsed = (totalTiles + T - 1) / T;
    int blocks = (wavesUsed + 3) / 4;
    k_dec<<<blocks, 256, 0, stream>>>(zbuf, ei, wfrag,
        db[0], db[1], db[2], db[3], db[4], out, E, T, totalTiles);
}

// Round 8
// 539.602 us; speedup vs baseline: 1.0766x; 1.0766x over previous
//
#include <hip/hip_runtime.h>
#include <hip/hip_bf16.h>
#include <math.h>

using short8 = __attribute__((ext_vector_type(8))) short;
using f32x4  = __attribute__((ext_vector_type(4))) float;

__device__ __forceinline__ unsigned short f2bf(float x) {
    return __builtin_bit_cast(unsigned short, __float2bfloat16(x));
}
__device__ __forceinline__ float bf2f(unsigned short u) {
    unsigned int x = ((unsigned int)u) << 16;
    return __builtin_bit_cast(float, x);
}

#define MFMA16(A,B,C) __builtin_amdgcn_mfma_f32_16x16x32_bf16((A),(B),(C),0,0,0)

// ---------------- helpers ----------------
__device__ __forceinline__ void ld16(const float* __restrict__ p, float* a) {
    const float4* q = (const float4*)p;
    float4 v0 = q[0], v1 = q[1], v2 = q[2], v3 = q[3];
    a[0]=v0.x; a[1]=v0.y; a[2]=v0.z; a[3]=v0.w;
    a[4]=v1.x; a[5]=v1.y; a[6]=v1.z; a[7]=v1.w;
    a[8]=v2.x; a[9]=v2.y; a[10]=v2.z; a[11]=v2.w;
    a[12]=v3.x; a[13]=v3.y; a[14]=v3.z; a[15]=v3.w;
}

// ---------------- CSR build ----------------
__global__ __launch_bounds__(256) void k_count(const int* __restrict__ ei, int* __restrict__ cnt, int E) {
    int e = blockIdx.x * blockDim.x + threadIdx.x;
    if (e < E) atomicAdd(&cnt[ei[E + e]], 1);
}

__global__ __launch_bounds__(256) void k_scanA(const int* __restrict__ cnt, int* __restrict__ offs,
                                               int* __restrict__ bsum, int N) {
    __shared__ int s[256];
    int i = blockIdx.x * 256 + threadIdx.x;
    int v = (i < N) ? cnt[i] : 0;
    s[threadIdx.x] = v;
    __syncthreads();
    #pragma unroll
    for (int d = 1; d < 256; d <<= 1) {
        int t = (threadIdx.x >= d) ? s[threadIdx.x - d] : 0;
        __syncthreads();
        s[threadIdx.x] += t;
        __syncthreads();
    }
    if (i < N) offs[i] = s[threadIdx.x] - v;
    if (threadIdx.x == 255) bsum[blockIdx.x] = s[255];
}

__global__ __launch_bounds__(256) void k_scanB(int* __restrict__ bsum, int nb) {
    __shared__ int s[256];
    int v = (threadIdx.x < nb) ? bsum[threadIdx.x] : 0;
    s[threadIdx.x] = v;
    __syncthreads();
    #pragma unroll
    for (int d = 1; d < 256; d <<= 1) {
        int t = (threadIdx.x >= d) ? s[threadIdx.x - d] : 0;
        __syncthreads();
        s[threadIdx.x] += t;
        __syncthreads();
    }
    if (threadIdx.x < nb) bsum[threadIdx.x] = s[threadIdx.x] - v;
}

__global__ __launch_bounds__(256) void k_scanC(int* __restrict__ offs, const int* __restrict__ bsum, int N) {
    int i = blockIdx.x * 256 + threadIdx.x;
    if (i < N) offs[i] += bsum[blockIdx.x];
}

__global__ __launch_bounds__(256) void k_fillD(const int* __restrict__ ei, const int* __restrict__ offs,
                                               int* __restrict__ cursor, int* __restrict__ slotOf,
                                               int* __restrict__ srcSl, int E) {
    int e = blockIdx.x * blockDim.x + threadIdx.x;
    if (e < E) {
        int d = ei[E + e];
        int slot = offs[d] + atomicAdd(&cursor[d], 1);
        slotOf[e] = slot;
        srcSl[slot] = ei[e];
    }
}

// ---------------- edge MLP a = relu(ea@w1+b1), stored in slot order (once) ----------------
__global__ __launch_bounds__(256) void k_a(
    const float* __restrict__ ea, const float* __restrict__ w1,
    const float* __restrict__ b1, const int* __restrict__ slotOf,
    float* __restrict__ aSl, int E)
{
    int e = blockIdx.x * 256 + threadIdx.x;
    if (e >= E) return;
    const float4* p = (const float4*)(ea + (size_t)e * 8);
    float4 v0 = p[0], v1 = p[1];
    float eav[8] = {v0.x, v0.y, v0.z, v0.w, v1.x, v1.y, v1.z, v1.w};
    float a[16];
    #pragma unroll
    for (int k = 0; k < 16; k++) a[k] = b1[k];
    #pragma unroll
    for (int q = 0; q < 8; q++) {
        float ev = eav[q];
        #pragma unroll
        for (int k = 0; k < 16; k++) a[k] += ev * w1[q * 16 + k];
    }
    int slot = slotOf[e];
    float4* o = (float4*)(aSl + (size_t)slot * 16);
    o[0] = make_float4(fmaxf(a[0],0.f), fmaxf(a[1],0.f), fmaxf(a[2],0.f), fmaxf(a[3],0.f));
    o[1] = make_float4(fmaxf(a[4],0.f), fmaxf(a[5],0.f), fmaxf(a[6],0.f), fmaxf(a[7],0.f));
    o[2] = make_float4(fmaxf(a[8],0.f), fmaxf(a[9],0.f), fmaxf(a[10],0.f), fmaxf(a[11],0.f));
    o[3] = make_float4(fmaxf(a[12],0.f), fmaxf(a[13],0.f), fmaxf(a[14],0.f), fmaxf(a[15],0.f));
}

// ---------------- per-layer gather: hSl[slot][c] = BN(h[srcSl[slot]][c]) ----------------
template<int BNPREV>
__global__ __launch_bounds__(256) void k_gather(
    const float* __restrict__ hraw, const int* __restrict__ srcSl,
    const float* __restrict__ statsPrev, const float* __restrict__ gPrev,
    const float* __restrict__ bePrev, float* __restrict__ hSl,
    int E16, float invN)
{
    __shared__ float scsh[32];
    if (BNPREV) {
        if (threadIdx.x < 16) {
            int o = threadIdx.x;
            float m = statsPrev[o] * invN;
            float var = statsPrev[16 + o] * invN - m * m;
            float sc = gPrev[o] * rsqrtf(var + 1e-5f);
            scsh[o] = sc;
            scsh[16 + o] = bePrev[o] - m * sc;
        }
        __syncthreads();
    }
    int t = blockIdx.x * 256 + threadIdx.x;
    if (t >= E16) return;
    int slot = t >> 4, c = t & 15;
    int src = srcSl[slot];
    float v = hraw[(size_t)src * 16 + c];
    if (BNPREV) v = v * scsh[c] + scsh[16 + c];
    hSl[t] = v;
}

// ---------------- W2cat fragment prep (once): logical K = i*18+k, K=288 = 9 tiles ----------
__global__ void k_w2prep(const float* __restrict__ w2, const float* __restrict__ b2,
                         const float* __restrict__ r0, const float* __restrict__ r1,
                         const float* __restrict__ r2, const float* __restrict__ r3,
                         unsigned short* __restrict__ wf2)
{
    int tid = blockIdx.x * 256 + threadIdx.x;
    if (tid >= 2304) return;                      // 4 layers * 9 tiles * 64 lanes
    int l = tid / 576, rem = tid % 576;
    int t = rem / 64, lane = rem % 64;
    int g = lane >> 4, o = lane & 15;
    const float* roots[4] = {r0, r1, r2, r3};
    unsigned short hi8[8], lo8[8];
    #pragma unroll
    for (int j = 0; j < 8; j++) {
        int kp = 32 * t + 8 * g + j;
        int i = kp / 18, k = kp % 18;
        float v;
        if (k < 16)      v = w2[k * 256 + i * 16 + o];
        else if (k == 16) v = b2[i * 16 + o];
        else              v = roots[l][i * 16 + o];
        unsigned short h = f2bf(v);
        hi8[j] = h;
        lo8[j] = f2bf(v - bf2f(h));
    }
    unsigned short* oh = wf2 + (size_t)l * 9216 + (t * 2 + 0) * 512 + lane * 8;
    unsigned short* ol = wf2 + (size_t)l * 9216 + (t * 2 + 1) * 512 + lane * 8;
    #pragma unroll
    for (int j = 0; j < 8; j++) { oh[j] = hi8[j]; ol[j] = lo8[j]; }
}

// ---------------- fused conv layer v3: 4 waves share one 16-node tile -------------------
// 256 threads = 4 waves x (4 nodes x 16 channels) = 16 concurrent node deg-loops.
// Shared Bl (18.9KB) -> 8 blocks/CU; wave 0 alone does the 27-MFMA contraction.
template<int BNPREV>
__global__ __launch_bounds__(256) void k_fuse2(
    const float* __restrict__ hraw, const float* __restrict__ statsPrev,
    const float* __restrict__ gPrev, const float* __restrict__ bePrev,
    const int* __restrict__ offs, const int* __restrict__ cnt,
    const float* __restrict__ hSl, const float* __restrict__ aSl,
    const unsigned short* __restrict__ wfragL, const float* __restrict__ cb,
    float* __restrict__ hout, float* __restrict__ statsCur,
    int N, float invN)
{
    __shared__ unsigned short Bl[2][16][296];   // [hi/lo][n_local][k'] (stride 296)
    __shared__ float scsh[32];
    int tid = threadIdx.x;
    int w = tid >> 6, lane = tid & 63;
    int g = lane >> 4, c = lane & 15;
    if (BNPREV) {
        if (tid < 16) {
            float m = statsPrev[tid] * invN;
            float var = statsPrev[16 + tid] * invN - m * m;
            float sc = gPrev[tid] * rsqrtf(var + 1e-5f);
            scsh[tid] = sc;
            scsh[16 + tid] = bePrev[tid] - m * sc;
        }
        __syncthreads();
    }
    float scC = BNPREV ? scsh[c] : 1.f;
    float shC = BNPREV ? scsh[16 + c] : 0.f;
    int base = blockIdx.x * 16;
    int nl = w * 4 + g;                        // this lane's node (one per lane)
    int node = base + nl;

    const f32x4* aSl4 = (const f32x4*)aSl;

    float B[18];
    #pragma unroll
    for (int k = 0; k < 18; k++) B[k] = 0.f;
    if (node < N) {
        B[17] = hraw[(size_t)node * 16 + c] * scC + shC;   // hBN -> root row
        int start = offs[node], deg = cnt[node];
        #pragma unroll 1
        for (int j = 0; j < deg; j++) {
            size_t s0 = (size_t)(start + j);
            float hs0 = hSl[s0 * 16 + c];
            f32x4 a00 = aSl4[s0*4+0], a01 = aSl4[s0*4+1], a02 = aSl4[s0*4+2], a03 = aSl4[s0*4+3];
            #pragma unroll
            for (int q = 0; q < 4; q++) {
                B[q]      += a00[q]*hs0; B[4+q]  += a01[q]*hs0;
                B[8+q]    += a02[q]*hs0; B[12+q] += a03[q]*hs0;
            }
            B[16] += hs0;
        }
    }
    // write hi/lo planes: thread's 18 values contiguous at k' = c*18 + (0..17)
    #pragma unroll
    for (int p = 0; p < 9; p++) {
        float v0 = B[2*p], v1 = B[2*p+1];
        unsigned short h0 = f2bf(v0), h1 = f2bf(v1);
        unsigned short e0 = f2bf(v0 - bf2f(h0)), e1 = f2bf(v1 - bf2f(h1));
        *(unsigned int*)&Bl[0][nl][c*18 + 2*p] = (unsigned int)h0 | ((unsigned int)h1 << 16);
        *(unsigned int*)&Bl[1][nl][c*18 + 2*p] = (unsigned int)e0 | ((unsigned int)e1 << 16);
    }
    __syncthreads();

    if (w != 0) return;

    // ---- contraction (wave 0): A rows = n_local (lane&15); W frags share sigma ----
    float cbv = cb[c];
    f32x4 acc0 = {cbv, cbv, cbv, cbv};
    f32x4 acc1 = {0.f, 0.f, 0.f, 0.f};
    f32x4 acc2 = {0.f, 0.f, 0.f, 0.f};
    const short8* wf = (const short8*)wfragL;
    #pragma unroll
    for (int t = 0; t < 9; t++) {
        short8 whi = wf[(t*2+0)*64 + lane];
        short8 wlo = wf[(t*2+1)*64 + lane];
        short8 ahi = *(const short8*)&Bl[0][c][32*t + 8*g];
        short8 alo = *(const short8*)&Bl[1][c][32*t + 8*g];
        acc0 = MFMA16(ahi, whi, acc0);
        acc1 = MFMA16(ahi, wlo, acc1);
        acc2 = MFMA16(alo, whi, acc2);
    }

    float s1 = 0.f, s2 = 0.f;
    #pragma unroll
    for (int rr = 0; rr < 4; rr++) {
        int n2 = base + 4*g + rr;
        float v = fmaxf(acc0[rr] + acc1[rr] + acc2[rr], 0.f);
        if (n2 < N) {
            hout[(size_t)n2 * 16 + c] = v;
            s1 += v; s2 += v * v;
        }
    }
    s1 += __shfl_xor(s1, 16); s1 += __shfl_xor(s1, 32);
    s2 += __shfl_xor(s2, 16); s2 += __shfl_xor(s2, 32);
    if (lane < 16) {
        atomicAdd(&statsCur[c], s1);
        atomicAdd(&statsCur[16 + c], s2);
    }
}

// ---------------- mu / logvar / reparameterize (BN of layer 4 inlined) ----------------
__global__ __launch_bounds__(256) void k_z(
    const float* __restrict__ hraw, const float* __restrict__ stats4,
    const float* __restrict__ g4, const float* __restrict__ be4,
    const float* __restrict__ mu_w, const float* __restrict__ mu_b,
    const float* __restrict__ lv_w, const float* __restrict__ lv_b,
    const float* __restrict__ eps, float* __restrict__ z, int N, float invN)
{
    __shared__ float scsh[32];
    int tid = threadIdx.x;
    if (tid < 16) {
        float m = stats4[tid] * invN;
        float var = stats4[16 + tid] * invN - m * m;
        float sc = g4[tid] * rsqrtf(var + 1e-5f);
        scsh[tid] = sc;
        scsh[16 + tid] = be4[tid] - m * sc;
    }
    __syncthreads();
    int t = blockIdx.x * 256 + tid;
    if (t >= N * 16) return;
    int n = t >> 4, o = t & 15;
    float hr[16];
    ld16(hraw + (size_t)n * 16, hr);
    float mu = mu_b[o], lv = lv_b[o];
    #pragma unroll
    for (int j = 0; j < 16; j++) {
        float hv = hr[j] * scsh[j] + scsh[16 + j];
        mu += hv * mu_w[j * 16 + o];
        lv += hv * lv_w[j * 16 + o];
    }
    lv = fminf(lv, 10.f);
    z[t] = mu + eps[t] * expf(0.5f * lv);
}

// ---------------- decoder weight pre-swizzle to MFMA fragment order (bf16) ----------------
__global__ void k_wprep(const float* __restrict__ dw0, const float* __restrict__ dw1,
                        const float* __restrict__ dw2, const float* __restrict__ dw3,
                        const float* __restrict__ dw4, unsigned short* __restrict__ wfrag)
{
    int tid = blockIdx.x * 256 + threadIdx.x;
    if (tid >= 1920) return;
    int f = tid >> 6, lane = tid & 63, g = lane >> 4, c = lane & 15;
    float v[8];
    if (f < 4) {
        int mt = f;
        #pragma unroll
        for (int j = 0; j < 8; j++) v[j] = dw0[(8*g + j) * 64 + 16*mt + c];
    } else if (f < 28) {
        int fl = f - 4;
        const float* W = (fl >> 3) == 0 ? dw1 : ((fl >> 3) == 1 ? dw2 : dw3);
        int mt = (fl & 7) >> 1, kt = fl & 1;
        #pragma unroll
        for (int j = 0; j < 8; j++) {
            int in = 16*(2*kt + (j>>2)) + 4*g + (j&3);
            v[j] = W[in * 64 + 16*mt + c];
        }
    } else {
        int kt = f - 28;
        #pragma unroll
        for (int j = 0; j < 8; j++) {
            int in = 16*(2*kt + (j>>2)) + 4*g + (j&3);
            v[j] = (c < 8) ? dw4[in * 8 + c] : 0.f;
        }
    }
    unsigned short* o = wfrag + (size_t)tid * 8;
    #pragma unroll
    for (int j = 0; j < 8; j++) o[j] = f2bf(v[j]);
}

// ---------------- MFMA decoder ----------------
#define REPACK() do { \
    float av[16]; \
    _Pragma("unroll") for (int mt = 0; mt < 4; mt++) { \
        _Pragma("unroll") for (int r = 0; r < 4; r++) av[mt*4 + r] = acc[mt][r]; } \
    _Pragma("unroll") for (int kt = 0; kt < 2; kt++) { \
        _Pragma("unroll") for (int j = 0; j < 8; j++) \
            a2[kt][j] = (short)f2bf(fmaxf(av[(2*kt + (j>>2))*4 + (j&3)], 0.f)); } \
} while (0)

#define DENSE(WF, DB) do { \
    _Pragma("unroll") for (int mt = 0; mt < 4; mt++) acc[mt] = *(const f32x4*)((DB) + 16*mt + 4*g); \
    _Pragma("unroll") for (int mt = 0; mt < 4; mt++) acc[mt] = MFMA16(WF[mt][0], a2[0], acc[mt]); \
    _Pragma("unroll") for (int mt = 0; mt < 4; mt++) acc[mt] = MFMA16(WF[mt][1], a2[1], acc[mt]); \
    REPACK(); \
} while (0)

__global__ __launch_bounds__(256) void k_dec(
    const float* __restrict__ z, const int* __restrict__ ei,
    const unsigned short* __restrict__ wfrag,
    const float* __restrict__ db0, const float* __restrict__ db1,
    const float* __restrict__ db2, const float* __restrict__ db3,
    const float* __restrict__ db4,
    float* __restrict__ out, int E, int T, int totalTiles)
{
    int wid = blockIdx.x * 4 + (threadIdx.x >> 6);
    int lane = threadIdx.x & 63;
    int g = lane >> 4, c = lane & 15;
    int t0 = wid * T;
    if (t0 >= totalTiles) return;
    int t1 = min(t0 + T, totalTiles);

    const short8* wf = (const short8*)wfrag;
    short8 w0f[4], wfa[4][2], wfb[4][2], wfc[4][2], w4f[2];
    #pragma unroll
    for (int mt = 0; mt < 4; mt++) w0f[mt] = wf[mt * 64 + lane];
    #pragma unroll
    for (int mt = 0; mt < 4; mt++) {
        #pragma unroll
        for (int kt = 0; kt < 2; kt++) {
            wfa[mt][kt] = wf[(4  + mt*2 + kt) * 64 + lane];
            wfb[mt][kt] = wf[(12 + mt*2 + kt) * 64 + lane];
            wfc[mt][kt] = wf[(20 + mt*2 + kt) * 64 + lane];
        }
    }
    w4f[0] = wf[28 * 64 + lane];
    w4f[1] = wf[29 * 64 + lane];

    int eiOfs = (g < 2) ? 0 : E;
    int zofs = (g & 1) * 8;

    int node = ei[eiOfs + min(t0 * 16 + c, E - 1)];
    f32x4 zv0 = *(const f32x4*)(z + (size_t)node * 16 + zofs);
    f32x4 zv1 = *(const f32x4*)(z + (size_t)node * 16 + zofs + 4);
    int node_n = 0;
    if (t0 + 1 < t1) node_n = ei[eiOfs + min((t0 + 1) * 16 + c, E - 1)];

    for (int t = t0; t < t1; ++t) {
        f32x4 zn0 = {0.f,0.f,0.f,0.f}, zn1 = {0.f,0.f,0.f,0.f};
        if (t + 1 < t1) {
            zn0 = *(const f32x4*)(z + (size_t)node_n * 16 + zofs);
            zn1 = *(const f32x4*)(z + (size_t)node_n * 16 + zofs + 4);
        }
        int node_nn = 0;
        if (t + 2 < t1) node_nn = ei[eiOfs + min((t + 2) * 16 + c, E - 1)];

        short8 af0;
        #pragma unroll
        for (int j = 0; j < 4; j++) {
            af0[j]     = (short)f2bf(zv0[j]);
            af0[4 + j] = (short)f2bf(zv1[j]);
        }
        f32x4 acc[4];
        short8 a2[2];
        #pragma unroll
        for (int mt = 0; mt < 4; mt++) acc[mt] = *(const f32x4*)(db0 + 16*mt + 4*g);
        #pragma unroll
        for (int mt = 0; mt < 4; mt++) acc[mt] = MFMA16(w0f[mt], af0, acc[mt]);
        REPACK();

        DENSE(wfa, db1);
        DENSE(wfb, db2);
        DENSE(wfc, db3);

        f32x4 o4;
        if (g < 2) o4 = *(const f32x4*)(db4 + 4*g);
        else { o4[0]=0.f; o4[1]=0.f; o4[2]=0.f; o4[3]=0.f; }
        o4 = MFMA16(w4f[0], a2[0], o4);
        o4 = MFMA16(w4f[1], a2[1], o4);

        int e = t * 16 + c;
        if (g < 2 && e < E) *(f32x4*)(out + (size_t)e * 8 + 4*g) = o4;

        zv0 = zn0; zv1 = zn1; node_n = node_nn;
    }
}

// ---------------- launch ----------------
extern "C" void kernel_launch(void* const* d_in, const int* in_sizes, int n_in,
                              void* d_out, int out_size, void* d_ws, size_t ws_size,
                              hipStream_t stream)
{
    const float* x   = (const float*)d_in[0];
    const int*   ei  = (const int*)d_in[1];
    const float* ea  = (const float*)d_in[2];
    const float* eps = (const float*)d_in[3];
    const float* w1  = (const float*)d_in[4];
    const float* b1  = (const float*)d_in[5];
    const float* w2  = (const float*)d_in[6];
    const float* b2  = (const float*)d_in[7];
    const float* root[4]; const float* cb[4]; const float* g[4]; const float* be[4];
    for (int l = 0; l < 4; l++) {
        root[l] = (const float*)d_in[8 + 4*l];
        cb[l]   = (const float*)d_in[9 + 4*l];
        g[l]    = (const float*)d_in[10 + 4*l];
        be[l]   = (const float*)d_in[11 + 4*l];
    }
    const float* mu_w = (const float*)d_in[24];
    const float* mu_b = (const float*)d_in[25];
    const float* lv_w = (const float*)d_in[26];
    const float* lv_b = (const float*)d_in[27];
    const float* dw[5]; const float* db[5];
    for (int i = 0; i < 5; i++) {
        dw[i] = (const float*)d_in[28 + 2*i];
        db[i] = (const float*)d_in[29 + 2*i];
    }
    float* out = (float*)d_out;

    int N = in_sizes[0] / 16;
    int E = in_sizes[2] / 8;
    float invN = 1.0f / N;

    // ---- workspace layout ----
    int*   cnt      = (int*)d_ws;                 // N
    int*   cursor   = cnt + N;                    // N
    float* statsAll = (float*)(cursor + N);       // 128 (4 layers x 32)
    int*   offs     = (int*)(statsAll + 128);     // N
    int*   bsum     = offs + N;                   // 256
    int*   slotOf   = bsum + 256;                 // E
    int*   srcSl    = slotOf + E;                 // E
    float* aSl      = (float*)(srcSl + E);        // E*16
    float* hSl      = aSl + (size_t)E * 16;       // E*16
    float* hA       = hSl + (size_t)E * 16;       // N*16
    float* hB       = hA + (size_t)N * 16;        // N*16
    float* zbuf     = hB + (size_t)N * 16;        // N*16
    unsigned short* wfrag  = (unsigned short*)(zbuf + (size_t)N * 16); // 15360 (decoder)
    unsigned short* wfrag2 = wfrag + 15360;       // 36864 (conv W2cat hi/lo, 4 layers)

    int nbScan = (N + 255) / 256;

    hipMemsetAsync(cnt, 0, ((size_t)2 * N + 128) * sizeof(int), stream);

    // ---- weight preps (independent) ----
    k_wprep<<<8, 256, 0, stream>>>(dw[0], dw[1], dw[2], dw[3], dw[4], wfrag);
    k_w2prep<<<9, 256, 0, stream>>>(w2, b2, root[0], root[1], root[2], root[3], wfrag2);

    // ---- dst-CSR ----
    k_count<<<(E + 255) / 256, 256, 0, stream>>>(ei, cnt, E);
    k_scanA<<<nbScan, 256, 0, stream>>>(cnt, offs, bsum, N);
    k_scanB<<<1, 256, 0, stream>>>(bsum, nbScan);
    k_scanC<<<nbScan, 256, 0, stream>>>(offs, bsum, N);
    k_fillD<<<(E + 255) / 256, 256, 0, stream>>>(ei, offs, cursor, slotOf, srcSl, E);

    // ---- edge MLP once (layer-independent) ----
    k_a<<<(E + 255) / 256, 256, 0, stream>>>(ea, w1, b1, slotOf, aSl, E);

    int E16 = E * 16;
    int nbG = (E16 + 255) / 256;
    int nbF = (N + 15) / 16;

    // ---- 4 conv layers: gather(BN) -> fuse2 ----
    k_gather<0><<<nbG, 256, 0, stream>>>(x, srcSl, nullptr, nullptr, nullptr, hSl, E16, invN);
    k_fuse2<0><<<nbF, 256, 0, stream>>>(x, nullptr, nullptr, nullptr, offs, cnt, hSl, aSl,
                                        wfrag2 + 0 * 9216, cb[0], hA, statsAll + 0, N, invN);

    k_gather<1><<<nbG, 256, 0, stream>>>(hA, srcSl, statsAll + 0, g[0], be[0], hSl, E16, invN);
    k_fuse2<1><<<nbF, 256, 0, stream>>>(hA, statsAll + 0, g[0], be[0], offs, cnt, hSl, aSl,
                                        wfrag2 + 1 * 9216, cb[1], hB, statsAll + 32, N, invN);

    k_gather<1><<<nbG, 256, 0, stream>>>(hB, srcSl, statsAll + 32, g[1], be[1], hSl, E16, invN);
    k_fuse2<1><<<nbF, 256, 0, stream>>>(hB, statsAll + 32, g[1], be[1], offs, cnt, hSl, aSl,
                                        wfrag2 + 2 * 9216, cb[2], hA, statsAll + 64, N, invN);

    k_gather<1><<<nbG, 256, 0, stream>>>(hA, srcSl, statsAll + 64, g[2], be[2], hSl, E16, invN);
    k_fuse2<1><<<nbF, 256, 0, stream>>>(hA, statsAll + 64, g[2], be[2], offs, cnt, hSl, aSl,
                                        wfrag2 + 3 * 9216, cb[3], hB, statsAll + 96, N, invN);

    k_z<<<(N * 16 + 255) / 256, 256, 0, stream>>>(hB, statsAll + 96, g[3], be[3],
                                                  mu_w, mu_b, lv_w, lv_b, eps, zbuf, N, invN);

    int totalTiles = (E + 15) >> 4;
    int T = (totalTiles + 4095) / 4096;
    int wavesUsed = (totalTiles + T - 1) / T;
    int blocks = (wavesUsed + 3) / 4;
    k_dec<<<blocks, 256, 0, stream>>>(zbuf, ei, wfrag,
        db[0], db[1], db[2], db[3], db[4], out, E, T, totalTiles);
}

// Round 9
// 379.597 us; speedup vs baseline: 1.5305x; 1.4215x over previous
//
#include <hip/hip_runtime.h>
#include <hip/hip_bf16.h>
#include <math.h>

using short8 = __attribute__((ext_vector_type(8))) short;
using f32x4  = __attribute__((ext_vector_type(4))) float;

__device__ __forceinline__ unsigned short f2bf(float x) {
    return __builtin_bit_cast(unsigned short, __float2bfloat16(x));
}
__device__ __forceinline__ float bf2f(unsigned short u) {
    unsigned int x = ((unsigned int)u) << 16;
    return __builtin_bit_cast(float, x);
}

#define MFMA16(A,B,C) __builtin_amdgcn_mfma_f32_16x16x32_bf16((A),(B),(C),0,0,0)

// ---------------- helpers ----------------
__device__ __forceinline__ void ld16(const float* __restrict__ p, float* a) {
    const float4* q = (const float4*)p;
    float4 v0 = q[0], v1 = q[1], v2 = q[2], v3 = q[3];
    a[0]=v0.x; a[1]=v0.y; a[2]=v0.z; a[3]=v0.w;
    a[4]=v1.x; a[5]=v1.y; a[6]=v1.z; a[7]=v1.w;
    a[8]=v2.x; a[9]=v2.y; a[10]=v2.z; a[11]=v2.w;
    a[12]=v3.x; a[13]=v3.y; a[14]=v3.z; a[15]=v3.w;
}

// ---------------- CSR build ----------------
__global__ __launch_bounds__(256) void k_count(const int* __restrict__ ei, int* __restrict__ cnt, int E) {
    int e = blockIdx.x * blockDim.x + threadIdx.x;
    if (e < E) atomicAdd(&cnt[ei[E + e]], 1);
}

__global__ __launch_bounds__(256) void k_scanA(const int* __restrict__ cnt, int* __restrict__ offs,
                                               int* __restrict__ bsum, int N) {
    __shared__ int s[256];
    int i = blockIdx.x * 256 + threadIdx.x;
    int v = (i < N) ? cnt[i] : 0;
    s[threadIdx.x] = v;
    __syncthreads();
    #pragma unroll
    for (int d = 1; d < 256; d <<= 1) {
        int t = (threadIdx.x >= d) ? s[threadIdx.x - d] : 0;
        __syncthreads();
        s[threadIdx.x] += t;
        __syncthreads();
    }
    if (i < N) offs[i] = s[threadIdx.x] - v;
    if (threadIdx.x == 255) bsum[blockIdx.x] = s[255];
}

__global__ __launch_bounds__(256) void k_scanB(int* __restrict__ bsum, int nb) {
    __shared__ int s[256];
    int v = (threadIdx.x < nb) ? bsum[threadIdx.x] : 0;
    s[threadIdx.x] = v;
    __syncthreads();
    #pragma unroll
    for (int d = 1; d < 256; d <<= 1) {
        int t = (threadIdx.x >= d) ? s[threadIdx.x - d] : 0;
        __syncthreads();
        s[threadIdx.x] += t;
        __syncthreads();
    }
    if (threadIdx.x < nb) bsum[threadIdx.x] = s[threadIdx.x] - v;
}

__global__ __launch_bounds__(256) void k_scanC(int* __restrict__ offs, const int* __restrict__ bsum, int N) {
    int i = blockIdx.x * 256 + threadIdx.x;
    if (i < N) offs[i] += bsum[blockIdx.x];
}

__global__ __launch_bounds__(256) void k_fillD(const int* __restrict__ ei, const int* __restrict__ offs,
                                               int* __restrict__ cursor, int* __restrict__ slotOf,
                                               int* __restrict__ srcSl, int E) {
    int e = blockIdx.x * blockDim.x + threadIdx.x;
    if (e < E) {
        int d = ei[E + e];
        int slot = offs[d] + atomicAdd(&cursor[d], 1);
        slotOf[e] = slot;
        srcSl[slot] = ei[e];
    }
}

// ---------------- edge MLP a = relu(ea@w1+b1), stored in slot order (once) ----------------
__global__ __launch_bounds__(256) void k_a(
    const float* __restrict__ ea, const float* __restrict__ w1,
    const float* __restrict__ b1, const int* __restrict__ slotOf,
    float* __restrict__ aSl, int E)
{
    int e = blockIdx.x * 256 + threadIdx.x;
    if (e >= E) return;
    const float4* p = (const float4*)(ea + (size_t)e * 8);
    float4 v0 = p[0], v1 = p[1];
    float eav[8] = {v0.x, v0.y, v0.z, v0.w, v1.x, v1.y, v1.z, v1.w};
    float a[16];
    #pragma unroll
    for (int k = 0; k < 16; k++) a[k] = b1[k];
    #pragma unroll
    for (int q = 0; q < 8; q++) {
        float ev = eav[q];
        #pragma unroll
        for (int k = 0; k < 16; k++) a[k] += ev * w1[q * 16 + k];
    }
    int slot = slotOf[e];
    float4* o = (float4*)(aSl + (size_t)slot * 16);
    o[0] = make_float4(fmaxf(a[0],0.f), fmaxf(a[1],0.f), fmaxf(a[2],0.f), fmaxf(a[3],0.f));
    o[1] = make_float4(fmaxf(a[4],0.f), fmaxf(a[5],0.f), fmaxf(a[6],0.f), fmaxf(a[7],0.f));
    o[2] = make_float4(fmaxf(a[8],0.f), fmaxf(a[9],0.f), fmaxf(a[10],0.f), fmaxf(a[11],0.f));
    o[3] = make_float4(fmaxf(a[12],0.f), fmaxf(a[13],0.f), fmaxf(a[14],0.f), fmaxf(a[15],0.f));
}

// ---------------- W2cat fragment prep (once): logical K = i*18+k, K=288 = 9 tiles ----------
__global__ void k_w2prep(const float* __restrict__ w2, const float* __restrict__ b2,
                         const float* __restrict__ r0, const float* __restrict__ r1,
                         const float* __restrict__ r2, const float* __restrict__ r3,
                         unsigned short* __restrict__ wf2)
{
    int tid = blockIdx.x * 256 + threadIdx.x;
    if (tid >= 2304) return;                      // 4 layers * 9 tiles * 64 lanes
    int l = tid / 576, rem = tid % 576;
    int t = rem / 64, lane = rem % 64;
    int g = lane >> 4, o = lane & 15;
    const float* roots[4] = {r0, r1, r2, r3};
    unsigned short hi8[8], lo8[8];
    #pragma unroll
    for (int j = 0; j < 8; j++) {
        int kp = 32 * t + 8 * g + j;
        int i = kp / 18, k = kp % 18;
        float v;
        if (k < 16)      v = w2[k * 256 + i * 16 + o];
        else if (k == 16) v = b2[i * 16 + o];
        else              v = roots[l][i * 16 + o];
        unsigned short h = f2bf(v);
        hi8[j] = h;
        lo8[j] = f2bf(v - bf2f(h));
    }
    unsigned short* oh = wf2 + (size_t)l * 9216 + (t * 2 + 0) * 512 + lane * 8;
    unsigned short* ol = wf2 + (size_t)l * 9216 + (t * 2 + 1) * 512 + lane * 8;
    #pragma unroll
    for (int j = 0; j < 8; j++) { oh[j] = hi8[j]; ol[j] = lo8[j]; }
}

// ---------------- fused conv layer v4: MFMA edge accumulation + MFMA contraction ---------
// 256 threads = 4 waves; wave w owns nodes base+4w..+3 (one at a time, all 64 lanes).
// Per node, per 32-edge chunk (dst-CSR slots are contiguous per node):
//   B_raw[k][i] += a^T[16 x 32edges] x h[32edges x 16]  via 3 MFMAs (hi/lo on both sides).
// BN folded in epilogue: B_BN = sc[i]*B_raw + sh[i]*S[k], S[k]=sum_e a[k] (shfl-reduced).
// Rows k=16 (b2, val = sum_e hBN) and k=17 (root, val = hBN[node]) appended; then the
// verified 27-MFMA contraction vs W2cat (unchanged from R8).
// NOTE: w via readfirstlane => offs/cnt are wave-uniform s_loads (R4 lesson).
template<int BNPREV>
__global__ __launch_bounds__(256) void k_fuse3(
    const float* __restrict__ hraw, const float* __restrict__ statsPrev,
    const float* __restrict__ gPrev, const float* __restrict__ bePrev,
    const int* __restrict__ offs, const int* __restrict__ cnt,
    const int* __restrict__ srcSl, const float* __restrict__ aSl,
    const unsigned short* __restrict__ wfragL, const float* __restrict__ cb,
    float* __restrict__ hout, float* __restrict__ statsCur,
    int N, float invN)
{
    __shared__ unsigned short Bl[2][16][296];   // [hi/lo][n_local][k'=i*18+k] (stride 296)
    __shared__ float scsh[32];
    int tid = threadIdx.x;
    int w = __builtin_amdgcn_readfirstlane(tid >> 6);
    int lane = tid & 63;
    int g = lane >> 4, i = lane & 15;           // i: A-row (a-channel k) AND B-col (h-channel)
    if (BNPREV) {
        if (tid < 16) {
            float m = statsPrev[tid] * invN;
            float var = statsPrev[16 + tid] * invN - m * m;
            float sc = gPrev[tid] * rsqrtf(var + 1e-5f);
            scsh[tid] = sc;
            scsh[16 + tid] = bePrev[tid] - m * sc;
        }
        __syncthreads();
    }
    float scC = BNPREV ? scsh[i] : 1.f;
    float shC = BNPREV ? scsh[16 + i] : 0.f;
    int base = blockIdx.x * 16;

    for (int q = 0; q < 4; q++) {
        int node = base + w * 4 + q;            // wave-uniform
        int nvalid = node < N;
        int start = 0, deg = 0;
        if (nvalid) { start = offs[node]; deg = cnt[node]; }
        f32x4 accM = {0.f, 0.f, 0.f, 0.f};
        f32x4 accC = {0.f, 0.f, 0.f, 0.f};
        float sumh = 0.f, suma = 0.f;
        int nch = (deg + 31) >> 5;
        for (int ch = 0; ch < nch; ch++) {
            float av[8], hv[8];
            #pragma unroll
            for (int j = 0; j < 8; j++) {
                int sl = ch * 32 + 8 * g + j;   // slot-local; quarter g covers slots 8g+j
                bool ok = sl < deg;
                size_t slc = ok ? (size_t)(start + sl) : 0;
                float a = aSl[slc * 16 + i];    // lanes i=0..15: coalesced 64B row
                int src = srcSl[slc];           // uniform within quarter -> L1 broadcast
                float h = hraw[(size_t)src * 16 + i];
                av[j] = ok ? a : 0.f;
                hv[j] = ok ? h : 0.f;
            }
            short8 ah, al, hh, hl;
            #pragma unroll
            for (int j = 0; j < 8; j++) {
                unsigned short xa = f2bf(av[j]);
                ah[j] = (short)xa;
                al[j] = (short)f2bf(av[j] - bf2f(xa));
                unsigned short xh = f2bf(hv[j]);
                hh[j] = (short)xh;
                hl[j] = (short)f2bf(hv[j] - bf2f(xh));
                sumh += hv[j];
                suma += av[j];
            }
            accM = MFMA16(ah, hh, accM);        // main product
            accC = MFMA16(ah, hl, accC);        // + a*h_err
            accC = MFMA16(al, hh, accC);        // + a_err*h   (a_err*h_err ~2^-18, dropped)
        }
        sumh += __shfl_xor(sumh, 16); sumh += __shfl_xor(sumh, 32);  // full sum_e h[i]
        suma += __shfl_xor(suma, 16); suma += __shfl_xor(suma, 32);  // full S[k=i]

        int nl = w * 4 + q;
        float v0 = scC * (accM[0] + accC[0]) + shC * __shfl(suma, 4*g + 0);
        float v1 = scC * (accM[1] + accC[1]) + shC * __shfl(suma, 4*g + 1);
        float v2 = scC * (accM[2] + accC[2]) + shC * __shfl(suma, 4*g + 2);
        float v3 = scC * (accM[3] + accC[3]) + shC * __shfl(suma, 4*g + 3);
        unsigned short h0 = f2bf(v0), h1 = f2bf(v1), h2 = f2bf(v2), h3 = f2bf(v3);
        unsigned short l0 = f2bf(v0 - bf2f(h0)), l1 = f2bf(v1 - bf2f(h1));
        unsigned short l2 = f2bf(v2 - bf2f(h2)), l3 = f2bf(v3 - bf2f(h3));
        *(unsigned int*)&Bl[0][nl][i*18 + 4*g]     = (unsigned int)h0 | ((unsigned int)h1 << 16);
        *(unsigned int*)&Bl[0][nl][i*18 + 4*g + 2] = (unsigned int)h2 | ((unsigned int)h3 << 16);
        *(unsigned int*)&Bl[1][nl][i*18 + 4*g]     = (unsigned int)l0 | ((unsigned int)l1 << 16);
        *(unsigned int*)&Bl[1][nl][i*18 + 4*g + 2] = (unsigned int)l2 | ((unsigned int)l3 << 16);
        if (g == 0) {
            float v = scC * sumh + shC * (float)deg;       // sum_e hBN[i]
            unsigned short hh16 = f2bf(v);
            Bl[0][nl][i*18 + 16] = hh16;
            Bl[1][nl][i*18 + 16] = f2bf(v - bf2f(hh16));
        } else if (g == 1) {
            float hn = hraw[(size_t)(nvalid ? node : 0) * 16 + i];
            float v = scC * hn + shC;                       // hBN[node][i] (root row)
            unsigned short hh17 = f2bf(v);
            Bl[0][nl][i*18 + 17] = hh17;
            Bl[1][nl][i*18 + 17] = f2bf(v - bf2f(hh17));
        }
    }
    __syncthreads();

    if (w != 0) return;

    // ---- contraction (wave 0, verified in R8): A rows = n_local (lane&15) ----
    float cbv = cb[i];
    f32x4 acc0 = {cbv, cbv, cbv, cbv};
    f32x4 acc1 = {0.f, 0.f, 0.f, 0.f};
    f32x4 acc2 = {0.f, 0.f, 0.f, 0.f};
    const short8* wf = (const short8*)wfragL;
    #pragma unroll
    for (int t = 0; t < 9; t++) {
        short8 whi = wf[(t*2+0)*64 + lane];
        short8 wlo = wf[(t*2+1)*64 + lane];
        short8 ahi = *(const short8*)&Bl[0][i][32*t + 8*g];
        short8 alo = *(const short8*)&Bl[1][i][32*t + 8*g];
        acc0 = MFMA16(ahi, whi, acc0);
        acc1 = MFMA16(ahi, wlo, acc1);
        acc2 = MFMA16(alo, whi, acc2);
    }

    float s1 = 0.f, s2 = 0.f;
    #pragma unroll
    for (int rr = 0; rr < 4; rr++) {
        int n2 = base + 4*g + rr;
        float v = fmaxf(acc0[rr] + acc1[rr] + acc2[rr], 0.f);
        if (n2 < N) {
            hout[(size_t)n2 * 16 + i] = v;
            s1 += v; s2 += v * v;
        }
    }
    s1 += __shfl_xor(s1, 16); s1 += __shfl_xor(s1, 32);
    s2 += __shfl_xor(s2, 16); s2 += __shfl_xor(s2, 32);
    if (lane < 16) {
        atomicAdd(&statsCur[i], s1);
        atomicAdd(&statsCur[16 + i], s2);
    }
}

// ---------------- mu / logvar / reparameterize (BN of layer 4 inlined) ----------------
__global__ __launch_bounds__(256) void k_z(
    const float* __restrict__ hraw, const float* __restrict__ stats4,
    const float* __restrict__ g4, const float* __restrict__ be4,
    const float* __restrict__ mu_w, const float* __restrict__ mu_b,
    const float* __restrict__ lv_w, const float* __restrict__ lv_b,
    const float* __restrict__ eps, float* __restrict__ z, int N, float invN)
{
    __shared__ float scsh[32];
    int tid = threadIdx.x;
    if (tid < 16) {
        float m = stats4[tid] * invN;
        float var = stats4[16 + tid] * invN - m * m;
        float sc = g4[tid] * rsqrtf(var + 1e-5f);
        scsh[tid] = sc;
        scsh[16 + tid] = be4[tid] - m * sc;
    }
    __syncthreads();
    int t = blockIdx.x * 256 + tid;
    if (t >= N * 16) return;
    int n = t >> 4, o = t & 15;
    float hr[16];
    ld16(hraw + (size_t)n * 16, hr);
    float mu = mu_b[o], lv = lv_b[o];
    #pragma unroll
    for (int j = 0; j < 16; j++) {
        float hv = hr[j] * scsh[j] + scsh[16 + j];
        mu += hv * mu_w[j * 16 + o];
        lv += hv * lv_w[j * 16 + o];
    }
    lv = fminf(lv, 10.f);
    z[t] = mu + eps[t] * expf(0.5f * lv);
}

// ---------------- decoder weight pre-swizzle to MFMA fragment order (bf16) ----------------
__global__ void k_wprep(const float* __restrict__ dw0, const float* __restrict__ dw1,
                        const float* __restrict__ dw2, const float* __restrict__ dw3,
                        const float* __restrict__ dw4, unsigned short* __restrict__ wfrag)
{
    int tid = blockIdx.x * 256 + threadIdx.x;
    if (tid >= 1920) return;
    int f = tid >> 6, lane = tid & 63, g = lane >> 4, c = lane & 15;
    float v[8];
    if (f < 4) {
        int mt = f;
        #pragma unroll
        for (int j = 0; j < 8; j++) v[j] = dw0[(8*g + j) * 64 + 16*mt + c];
    } else if (f < 28) {
        int fl = f - 4;
        const float* W = (fl >> 3) == 0 ? dw1 : ((fl >> 3) == 1 ? dw2 : dw3);
        int mt = (fl & 7) >> 1, kt = fl & 1;
        #pragma unroll
        for (int j = 0; j < 8; j++) {
            int in = 16*(2*kt + (j>>2)) + 4*g + (j&3);
            v[j] = W[in * 64 + 16*mt + c];
        }
    } else {
        int kt = f - 28;
        #pragma unroll
        for (int j = 0; j < 8; j++) {
            int in = 16*(2*kt + (j>>2)) + 4*g + (j&3);
            v[j] = (c < 8) ? dw4[in * 8 + c] : 0.f;
        }
    }
    unsigned short* o = wfrag + (size_t)tid * 8;
    #pragma unroll
    for (int j = 0; j < 8; j++) o[j] = f2bf(v[j]);
}

// ---------------- MFMA decoder ----------------
#define REPACK() do { \
    float av[16]; \
    _Pragma("unroll") for (int mt = 0; mt < 4; mt++) { \
        _Pragma("unroll") for (int r = 0; r < 4; r++) av[mt*4 + r] = acc[mt][r]; } \
    _Pragma("unroll") for (int kt = 0; kt < 2; kt++) { \
        _Pragma("unroll") for (int j = 0; j < 8; j++) \
            a2[kt][j] = (short)f2bf(fmaxf(av[(2*kt + (j>>2))*4 + (j&3)], 0.f)); } \
} while (0)

#define DENSE(WF, DB) do { \
    _Pragma("unroll") for (int mt = 0; mt < 4; mt++) acc[mt] = *(const f32x4*)((DB) + 16*mt + 4*g); \
    _Pragma("unroll") for (int mt = 0; mt < 4; mt++) acc[mt] = MFMA16(WF[mt][0], a2[0], acc[mt]); \
    _Pragma("unroll") for (int mt = 0; mt < 4; mt++) acc[mt] = MFMA16(WF[mt][1], a2[1], acc[mt]); \
    REPACK(); \
} while (0)

__global__ __launch_bounds__(256) void k_dec(
    const float* __restrict__ z, const int* __restrict__ ei,
    const unsigned short* __restrict__ wfrag,
    const float* __restrict__ db0, const float* __restrict__ db1,
    const float* __restrict__ db2, const float* __restrict__ db3,
    const float* __restrict__ db4,
    float* __restrict__ out, int E, int T, int totalTiles)
{
    int wid = blockIdx.x * 4 + (threadIdx.x >> 6);
    int lane = threadIdx.x & 63;
    int g = lane >> 4, c = lane & 15;
    int t0 = wid * T;
    if (t0 >= totalTiles) return;
    int t1 = min(t0 + T, totalTiles);

    const short8* wf = (const short8*)wfrag;
    short8 w0f[4], wfa[4][2], wfb[4][2], wfc[4][2], w4f[2];
    #pragma unroll
    for (int mt = 0; mt < 4; mt++) w0f[mt] = wf[mt * 64 + lane];
    #pragma unroll
    for (int mt = 0; mt < 4; mt++) {
        #pragma unroll
        for (int kt = 0; kt < 2; kt++) {
            wfa[mt][kt] = wf[(4  + mt*2 + kt) * 64 + lane];
            wfb[mt][kt] = wf[(12 + mt*2 + kt) * 64 + lane];
            wfc[mt][kt] = wf[(20 + mt*2 + kt) * 64 + lane];
        }
    }
    w4f[0] = wf[28 * 64 + lane];
    w4f[1] = wf[29 * 64 + lane];

    int eiOfs = (g < 2) ? 0 : E;
    int zofs = (g & 1) * 8;

    int node = ei[eiOfs + min(t0 * 16 + c, E - 1)];
    f32x4 zv0 = *(const f32x4*)(z + (size_t)node * 16 + zofs);
    f32x4 zv1 = *(const f32x4*)(z + (size_t)node * 16 + zofs + 4);
    int node_n = 0;
    if (t0 + 1 < t1) node_n = ei[eiOfs + min((t0 + 1) * 16 + c, E - 1)];

    for (int t = t0; t < t1; ++t) {
        f32x4 zn0 = {0.f,0.f,0.f,0.f}, zn1 = {0.f,0.f,0.f,0.f};
        if (t + 1 < t1) {
            zn0 = *(const f32x4*)(z + (size_t)node_n * 16 + zofs);
            zn1 = *(const f32x4*)(z + (size_t)node_n * 16 + zofs + 4);
        }
        int node_nn = 0;
        if (t + 2 < t1) node_nn = ei[eiOfs + min((t + 2) * 16 + c, E - 1)];

        short8 af0;
        #pragma unroll
        for (int j = 0; j < 4; j++) {
            af0[j]     = (short)f2bf(zv0[j]);
            af0[4 + j] = (short)f2bf(zv1[j]);
        }
        f32x4 acc[4];
        short8 a2[2];
        #pragma unroll
        for (int mt = 0; mt < 4; mt++) acc[mt] = *(const f32x4*)(db0 + 16*mt + 4*g);
        #pragma unroll
        for (int mt = 0; mt < 4; mt++) acc[mt] = MFMA16(w0f[mt], af0, acc[mt]);
        REPACK();

        DENSE(wfa, db1);
        DENSE(wfb, db2);
        DENSE(wfc, db3);

        f32x4 o4;
        if (g < 2) o4 = *(const f32x4*)(db4 + 4*g);
        else { o4[0]=0.f; o4[1]=0.f; o4[2]=0.f; o4[3]=0.f; }
        o4 = MFMA16(w4f[0], a2[0], o4);
        o4 = MFMA16(w4f[1], a2[1], o4);

        int e = t * 16 + c;
        if (g < 2 && e < E) *(f32x4*)(out + (size_t)e * 8 + 4*g) = o4;

        zv0 = zn0; zv1 = zn1; node_n = node_nn;
    }
}

// ---------------- launch ----------------
extern "C" void kernel_launch(void* const* d_in, const int* in_sizes, int n_in,
                              void* d_out, int out_size, void* d_ws, size_t ws_size,
                              hipStream_t stream)
{
    const float* x   = (const float*)d_in[0];
    const int*   ei  = (const int*)d_in[1];
    const float* ea  = (const float*)d_in[2];
    const float* eps = (const float*)d_in[3];
    const float* w1  = (const float*)d_in[4];
    const float* b1  = (const float*)d_in[5];
    const float* w2  = (const float*)d_in[6];
    const float* b2  = (const float*)d_in[7];
    const float* root[4]; const float* cb[4]; const float* g[4]; const float* be[4];
    for (int l = 0; l < 4; l++) {
        root[l] = (const float*)d_in[8 + 4*l];
        cb[l]   = (const float*)d_in[9 + 4*l];
        g[l]    = (const float*)d_in[10 + 4*l];
        be[l]   = (const float*)d_in[11 + 4*l];
    }
    const float* mu_w = (const float*)d_in[24];
    const float* mu_b = (const float*)d_in[25];
    const float* lv_w = (const float*)d_in[26];
    const float* lv_b = (const float*)d_in[27];
    const float* dw[5]; const float* db[5];
    for (int i = 0; i < 5; i++) {
        dw[i] = (const float*)d_in[28 + 2*i];
        db[i] = (const float*)d_in[29 + 2*i];
    }
    float* out = (float*)d_out;

    int N = in_sizes[0] / 16;
    int E = in_sizes[2] / 8;
    float invN = 1.0f / N;

    // ---- workspace layout ----
    int*   cnt      = (int*)d_ws;                 // N
    int*   cursor   = cnt + N;                    // N
    float* statsAll = (float*)(cursor + N);       // 128 (4 layers x 32)
    int*   offs     = (int*)(statsAll + 128);     // N
    int*   bsum     = offs + N;                   // 256
    int*   slotOf   = bsum + 256;                 // E
    int*   srcSl    = slotOf + E;                 // E
    float* aSl      = (float*)(srcSl + E);        // E*16
    float* hA       = aSl + (size_t)E * 16;       // N*16
    float* hB       = hA + (size_t)N * 16;        // N*16
    float* zbuf     = hB + (size_t)N * 16;        // N*16
    unsigned short* wfrag  = (unsigned short*)(zbuf + (size_t)N * 16); // 15360 (decoder)
    unsigned short* wfrag2 = wfrag + 15360;       // 36864 (conv W2cat hi/lo, 4 layers)

    int nbScan = (N + 255) / 256;

    hipMemsetAsync(cnt, 0, ((size_t)2 * N + 128) * sizeof(int), stream);

    // ---- weight preps (independent) ----
    k_wprep<<<8, 256, 0, stream>>>(dw[0], dw[1], dw[2], dw[3], dw[4], wfrag);
    k_w2prep<<<9, 256, 0, stream>>>(w2, b2, root[0], root[1], root[2], root[3], wfrag2);

    // ---- dst-CSR ----
    k_count<<<(E + 255) / 256, 256, 0, stream>>>(ei, cnt, E);
    k_scanA<<<nbScan, 256, 0, stream>>>(cnt, offs, bsum, N);
    k_scanB<<<1, 256, 0, stream>>>(bsum, nbScan);
    k_scanC<<<nbScan, 256, 0, stream>>>(offs, bsum, N);
    k_fillD<<<(E + 255) / 256, 256, 0, stream>>>(ei, offs, cursor, slotOf, srcSl, E);

    // ---- edge MLP once (layer-independent) ----
    k_a<<<(E + 255) / 256, 256, 0, stream>>>(ea, w1, b1, slotOf, aSl, E);

    int nbF = (N + 15) / 16;

    // ---- 4 fused conv layers (gather + BN folded in; no hSl round-trip) ----
    k_fuse3<0><<<nbF, 256, 0, stream>>>(x,  nullptr,       nullptr, nullptr,
                                        offs, cnt, srcSl, aSl,
                                        wfrag2 + 0 * 9216, cb[0], hA, statsAll + 0,  N, invN);
    k_fuse3<1><<<nbF, 256, 0, stream>>>(hA, statsAll + 0,  g[0], be[0],
                                        offs, cnt, srcSl, aSl,
                                        wfrag2 + 1 * 9216, cb[1], hB, statsAll + 32, N, invN);
    k_fuse3<1><<<nbF, 256, 0, stream>>>(hB, statsAll + 32, g[1], be[1],
                                        offs, cnt, srcSl, aSl,
                                        wfrag2 + 2 * 9216, cb[2], hA, statsAll + 64, N, invN);
    k_fuse3<1><<<nbF, 256, 0, stream>>>(hA, statsAll + 64, g[2], be[2],
                                        offs, cnt, srcSl, aSl,
                                        wfrag2 + 3 * 9216, cb[3], hB, statsAll + 96, N, invN);

    k_z<<<(N * 16 + 255) / 256, 256, 0, stream>>>(hB, statsAll + 96, g[3], be[3],
                                                  mu_w, mu_b, lv_w, lv_b, eps, zbuf, N, invN);

    int totalTiles = (E + 15) >> 4;
    int T = (totalTiles + 4095) / 4096;
    int wavesUsed = (totalTiles + T - 1) / T;
    int blocks = (wavesUsed + 3) / 4;
    k_dec<<<blocks, 256, 0, stream>>>(zbuf, ei, wfrag,
        db[0], db[1], db[2], db[3], db[4], out, E, T, totalTiles);
}